// Round 7
// baseline (163.480 us; speedup 1.0000x reference)
//
#include <hip/hip_runtime.h>
#include <math.h>

#define IMG_H 512
#define IMG_W 512
#define KW 11
#define RAD 5
#define T 4                     // output rows per thread
#define NROWS (T + 2 * RAD)     // 14 input rows walked
#define NG (IMG_W / 4)          // 128 float4 column-groups per row

#define C1F (0.01f * 0.01f)
#define C2F (0.03f * 0.03f)

__device__ __forceinline__ float ssim_px(float mu1, float mu2, float sp) {
    float m12 = mu1 * mu2;
    float sigma = sp - m12;
    float sq = mu1 * mu1 + mu2 * mu2;
    return ((2.f * m12 + C1F) * (2.f * sigma + C2F)) / ((sq + C1F) * (sq + C2F));
}

// Round-7 theory: all prior versions were fully-unrolled ~28-48 KB bodies that
// miss the 32 KB I-cache; per-wave VALU issue was 6-10% and rose as code size
// fell (r2->r6). This version ROLLS the 14-row loop (~2 KB body, I$-resident).
//   - dataflow = r2/r5's verified 4-col x T=4 tap layout (absmax 0).
//   - vertical scatter weight w[i-o] has a runtime index -> read from an
//     11-float LDS mirror (wave-uniform broadcast); static h-conv uses SGPR w.
//     Out-of-range taps add 0.0f*h (bit-exact no-op; acc never -0).
//   - allocator law (r0-r5): cap ~= 256/min_waves -> (256,2) = 128-reg cap,
//     fits the ~115-reg body honestly at 4 waves/SIMD. (256,4) would spill.
__global__ __launch_bounds__(256, 2)
void ssim_fused_kernel(const float* __restrict__ A, const float* __restrict__ B,
                       float* __restrict__ out, float inv_total) {
    __shared__ float wlds[KW];
    __shared__ float wpart[4];

    const int tid = threadIdx.x;
    const int g = tid & (NG - 1);        // col-group 0..127
    const int rchunk = tid >> 7;         // 0..1 (wave-uniform)
    const int img = blockIdx.y;
    const int ybase = blockIdx.x * (2 * T) + rchunk * T;   // first output row

    // Gaussian weights (sigma=1.5, K=11) — fp32 recipe matching np bit-exactly.
    float w[KW];
    {
        float s = 0.f;
#pragma unroll
        for (int i = 0; i < KW; ++i) {
            float d = (float)(i - RAD);
            w[i] = expf(-(d * d) / 4.5f);
            s += w[i];
        }
        float inv = 1.0f / s;
#pragma unroll
        for (int i = 0; i < KW; ++i) {
            w[i] *= inv;
            w[i] = __int_as_float(__builtin_amdgcn_readfirstlane(__float_as_int(w[i])));
        }
    }
    // LDS mirror for the runtime-indexed scatter weight (static stores only).
    if (tid == 0) {
        wlds[0] = w[0]; wlds[1] = w[1]; wlds[2]  = w[2];  wlds[3] = w[3];
        wlds[4] = w[4]; wlds[5] = w[5]; wlds[6]  = w[6];  wlds[7] = w[7];
        wlds[8] = w[8]; wlds[9] = w[9]; wlds[10] = w[10];
    }
    __syncthreads();

    const float* __restrict__ Ai = A + (size_t)img * IMG_H * IMG_W;
    const float* __restrict__ Bi = B + (size_t)img * IMG_H * IMG_W;
    const int c0 = 4 * g;

    float accA[T][4], accB[T][4], accP[T][4];
#pragma unroll
    for (int o = 0; o < T; ++o)
#pragma unroll
        for (int c = 0; c < 4; ++c) {
            accA[o][c] = 0.f; accB[o][c] = 0.f; accP[o][c] = 0.f;
        }

    // ---- Rolled walk over the 14 input rows (body ~2 KB, stays in I$).
#pragma unroll 1
    for (int i = 0; i < NROWS; ++i) {
        const int gy = ybase + i - RAD;
        if (gy >= 0 && gy < IMG_H) {     // wave-uniform (cheap s_cbranch)
            const float* rA = Ai + (size_t)gy * IMG_W;
            const float* rB = Bi + (size_t)gy * IMG_W;

            // Taps: cols c0-5 .. c0+8 -> fa[j] = col c0-5+j, j=0..13.
            // Halo guards are per-lane; masked lanes keep zeros (= padding).
            const float4 z4 = make_float4(0.f, 0.f, 0.f, 0.f);
            float4 va0 = z4, vb0 = z4, va2 = z4, vb2 = z4;
            if (g >= 1) {
                va0 = *(const float4*)(rA + c0 - 4);
                vb0 = *(const float4*)(rB + c0 - 4);
            }
            float4 va1 = *(const float4*)(rA + c0);
            float4 vb1 = *(const float4*)(rB + c0);
            if (g <= NG - 2) {
                va2 = *(const float4*)(rA + c0 + 4);
                vb2 = *(const float4*)(rB + c0 + 4);
            }
            float eaL = 0.f, ebL = 0.f, eaR = 0.f, ebR = 0.f;
            if (c0 - 5 >= 0)    { eaL = rA[c0 - 5]; ebL = rB[c0 - 5]; }
            if (c0 + 8 < IMG_W) { eaR = rA[c0 + 8]; ebR = rB[c0 + 8]; }

            float fa[14] = {eaL, va0.x, va0.y, va0.z, va0.w,
                            va1.x, va1.y, va1.z, va1.w,
                            va2.x, va2.y, va2.z, va2.w, eaR};
            float fb[14] = {ebL, vb0.x, vb0.y, vb0.z, vb0.w,
                            vb1.x, vb1.y, vb1.z, vb1.w,
                            vb2.x, vb2.y, vb2.z, vb2.w, ebR};
            float p[14];
#pragma unroll
            for (int j = 0; j < 14; ++j) p[j] = fa[j] * fb[j];

            // Horizontal 11-tap conv: col c uses fa[k+c], k ascending
            // (identical summation order to the verified rounds).
            float hA[4] = {0.f, 0.f, 0.f, 0.f};
            float hB[4] = {0.f, 0.f, 0.f, 0.f};
            float hP[4] = {0.f, 0.f, 0.f, 0.f};
#pragma unroll
            for (int k = 0; k < KW; ++k) {
                float wk = w[k];
#pragma unroll
                for (int c = 0; c < 4; ++c) {
                    hA[c] += wk * fa[k + c];
                    hB[c] += wk * fb[k + c];
                    hP[c] += wk * p[k + c];
                }
            }

            // Vertical scatter: output o gets weight w[i-o] when in range.
            // Runtime index -> LDS broadcast read; out-of-range adds 0.0f*h
            // (bit-exact no-op: acc is a sum of products, never -0).
#pragma unroll
            for (int o = 0; o < T; ++o) {
                int k = i - o;
                bool v = ((unsigned)k < (unsigned)KW);
                int kc = v ? k : 0;
                float wk = wlds[kc];
                wk = v ? wk : 0.f;
#pragma unroll
                for (int c = 0; c < 4; ++c) {
                    accA[o][c] += wk * hA[c];
                    accB[o][c] += wk * hB[c];
                    accP[o][c] += wk * hP[c];
                }
            }
        }
    }

    // SSIM formula per pixel + per-thread accumulate (16 px/thread).
    float acc = 0.f;
#pragma unroll
    for (int o = 0; o < T; ++o)
#pragma unroll
        for (int c = 0; c < 4; ++c)
            acc += ssim_px(accA[o][c], accB[o][c], accP[o][c]);

    // Reduce: wave shuffle -> LDS -> one atomic per block.
#pragma unroll
    for (int off = 32; off > 0; off >>= 1)
        acc += __shfl_down(acc, off, 64);
    int wid = tid >> 6;
    int lane = tid & 63;
    if (lane == 0) wpart[wid] = acc;
    __syncthreads();
    if (tid == 0) {
        float s = (wpart[0] + wpart[1]) + (wpart[2] + wpart[3]);
        atomicAdd(out, s * inv_total);
    }
}

extern "C" void kernel_launch(void* const* d_in, const int* in_sizes, int n_in,
                              void* d_out, int out_size, void* d_ws, size_t ws_size,
                              hipStream_t stream) {
    const float* A = (const float*)d_in[0];
    const float* B = (const float*)d_in[1];
    float* out = (float*)d_out;

    const int total = in_sizes[0];                 // 32*1*512*512
    const int nimg = total / (IMG_H * IMG_W);      // 32

    hipMemsetAsync(d_out, 0, sizeof(float), stream);

    dim3 grid(IMG_H / (2 * T), nimg, 1);           // (64, 32)
    ssim_fused_kernel<<<grid, 256, 0, stream>>>(A, B, out, 1.0f / (float)total);
}

// Round 8
// 145.532 us; speedup vs baseline: 1.1233x; 1.1233x over previous
//
#include <hip/hip_runtime.h>
#include <math.h>

#define IMG_H 512
#define IMG_W 512
#define KW 11
#define RAD 5
#define T 4                     // output rows per block
#define NROWS (T + 2 * RAD)     // 14 input rows
#define LROW 528                // 8 zero-pad + 512 cols + 8 zero-pad

#define C1F (0.01f * 0.01f)
#define C2F (0.03f * 0.03f)

__device__ __forceinline__ float ssim_px(float mu1, float mu2, float sp) {
    float m12 = mu1 * mu2;
    float sigma = sp - m12;
    float sq = mu1 * mu1 + mu2 * mu2;
    return ((2.f * m12 + C1F) * (2.f * sigma + C2F)) / ((sq + C1F) * (sq + C2F));
}

// Design Z (round 8): vertical-first separable conv + LDS halo exchange.
//
// Ledger: r2 80us/48% busy (unrolled, 64reg squeeze), r5 107us (prefetch,
// honest 88reg), r6 111us (LDS row staging), r7 97us/41% (rolled 2KB body,
// I$-resident -> I$ theory refuted). r7's VGPR=56 with zero spill proves the
// compiler SERIALIZES the 10 loads/iter into load->use chains when the
// working set (acc 48 + taps 28+) exceeds its register target -> ~2-3 serial
// ~700cy vmcnt stalls per iter = the 94% per-wave idle.
//
// Fix the SHAPE, not the schedule:
//   - vertical conv first: no horizontal halo -> thread owns 2 aligned cols,
//     2 float2 loads per row, 28 loads total (vs 140), zero divergent guards.
//   - all 14 rows in ra[]/rb[] (56 regs, static idx) -> all loads in flight,
//     ONE vmcnt wait. acc is only vA/vB/vP[T] float2 = 24 regs.
//   - LDS exchange (3 arrays x 4 rows x 528 = 25 KB) + 1 barrier, then
//     horizontal conv from LDS (float2 spans, dense, 2-way = conflict-free)
//     + SSIM, no accumulator arrays.
// Allocator law (r0-r5): (256,2) -> cap 128; structural demand ~100 regs.
__global__ __launch_bounds__(256, 2)
void ssim_fused_kernel(const float* __restrict__ A, const float* __restrict__ B,
                       float* __restrict__ out, float inv_total) {
    __shared__ float sV[3][T][LROW];    // 0:vA 1:vB 2:vP (vertical-conv results)
    __shared__ float wpart[4];

    const int tid = threadIdx.x;
    const int c0 = 2 * tid;             // this thread's 2 cols (0..510)
    const int img = blockIdx.y;
    const int ybase = blockIdx.x * T;   // first output row of the block

    // Gaussian weights (sigma=1.5, K=11) — fp32 recipe matching np bit-exactly.
    float w[KW];
    {
        float s = 0.f;
#pragma unroll
        for (int i = 0; i < KW; ++i) {
            float d = (float)(i - RAD);
            w[i] = expf(-(d * d) / 4.5f);
            s += w[i];
        }
        float inv = 1.0f / s;
#pragma unroll
        for (int i = 0; i < KW; ++i) {
            w[i] *= inv;
            w[i] = __int_as_float(__builtin_amdgcn_readfirstlane(__float_as_int(w[i])));
        }
    }

    // Zero the horizontal pads once (cols -8..-1 and 512..519; taps reach 517).
    if (tid < 8) {
#pragma unroll
        for (int a = 0; a < 3; ++a)
#pragma unroll
            for (int r = 0; r < T; ++r) {
                sV[a][r][tid] = 0.f;
                sV[a][r][520 + tid] = 0.f;
            }
    }

    const float* __restrict__ Ai = A + (size_t)img * IMG_H * IMG_W;
    const float* __restrict__ Bi = B + (size_t)img * IMG_H * IMG_W;

    // ---- Phase 1a: issue ALL 28 loads (static arrays, fully unrolled).
    // Row bound is wave-uniform; OOB rows stage zeros = vertical zero-padding.
    float2 ra[NROWS], rb[NROWS];
#pragma unroll
    for (int i = 0; i < NROWS; ++i) {
        int gy = ybase + i - RAD;
        float2 a = make_float2(0.f, 0.f);
        float2 b = make_float2(0.f, 0.f);
        if (gy >= 0 && gy < IMG_H) {
            a = *(const float2*)(Ai + (size_t)gy * IMG_W + c0);
            b = *(const float2*)(Bi + (size_t)gy * IMG_W + c0);
        }
        ra[i] = a; rb[i] = b;
    }

    // ---- Phase 1b: vertical 11-tap conv (scatter over the T output rows).
    float2 vA[T], vB[T], vP[T];
#pragma unroll
    for (int o = 0; o < T; ++o) {
        vA[o] = make_float2(0.f, 0.f);
        vB[o] = make_float2(0.f, 0.f);
        vP[o] = make_float2(0.f, 0.f);
    }
#pragma unroll
    for (int i = 0; i < NROWS; ++i) {
        float px = ra[i].x * rb[i].x;
        float py = ra[i].y * rb[i].y;
#pragma unroll
        for (int o = 0; o < T; ++o) {
            int k = i - o;                       // compile-time per (i,o)
            if (k >= 0 && k < KW) {
                float wk = w[k];
                vA[o].x += wk * ra[i].x; vA[o].y += wk * ra[i].y;
                vB[o].x += wk * rb[i].x; vB[o].y += wk * rb[i].y;
                vP[o].x += wk * px;      vP[o].y += wk * py;
            }
        }
    }

    // ---- Exchange: publish vertical results (dense float2, conflict-free).
#pragma unroll
    for (int o = 0; o < T; ++o) {
        *(float2*)&sV[0][o][c0 + 8] = vA[o];
        *(float2*)&sV[1][o][c0 + 8] = vB[o];
        *(float2*)&sV[2][o][c0 + 8] = vP[o];
    }
    __syncthreads();

    // ---- Phase 2: horizontal 11-tap conv from LDS + SSIM (no acc arrays).
    // f[m] = col c0-6+m = LDS idx c0+2+m, m=0..13 (even-aligned float2 reads).
    // col c0 tap k -> f[k+1]; col c0+1 tap k -> f[k+2]; k ascending.
    float acc = 0.f;
#pragma unroll
    for (int r = 0; r < T; ++r) {
        float2 qa[7], qb[7], qp[7];
#pragma unroll
        for (int j = 0; j < 7; ++j) {
            qa[j] = *(const float2*)&sV[0][r][c0 + 2 + 2 * j];
            qb[j] = *(const float2*)&sV[1][r][c0 + 2 + 2 * j];
            qp[j] = *(const float2*)&sV[2][r][c0 + 2 + 2 * j];
        }
        float fa[14] = {qa[0].x, qa[0].y, qa[1].x, qa[1].y, qa[2].x, qa[2].y,
                        qa[3].x, qa[3].y, qa[4].x, qa[4].y, qa[5].x, qa[5].y,
                        qa[6].x, qa[6].y};
        float fb[14] = {qb[0].x, qb[0].y, qb[1].x, qb[1].y, qb[2].x, qb[2].y,
                        qb[3].x, qb[3].y, qb[4].x, qb[4].y, qb[5].x, qb[5].y,
                        qb[6].x, qb[6].y};
        float fp[14] = {qp[0].x, qp[0].y, qp[1].x, qp[1].y, qp[2].x, qp[2].y,
                        qp[3].x, qp[3].y, qp[4].x, qp[4].y, qp[5].x, qp[5].y,
                        qp[6].x, qp[6].y};
        float h0A = 0.f, h1A = 0.f, h0B = 0.f, h1B = 0.f, h0P = 0.f, h1P = 0.f;
#pragma unroll
        for (int k = 0; k < KW; ++k) {
            float wk = w[k];
            h0A += wk * fa[k + 1]; h1A += wk * fa[k + 2];
            h0B += wk * fb[k + 1]; h1B += wk * fb[k + 2];
            h0P += wk * fp[k + 1]; h1P += wk * fp[k + 2];
        }
        acc += ssim_px(h0A, h0B, h0P);
        acc += ssim_px(h1A, h1B, h1P);
    }

    // Reduce: wave shuffle -> LDS -> one atomic per block.
#pragma unroll
    for (int off = 32; off > 0; off >>= 1)
        acc += __shfl_down(acc, off, 64);
    int wid = tid >> 6;
    int lane = tid & 63;
    if (lane == 0) wpart[wid] = acc;
    __syncthreads();
    if (tid == 0) {
        float s = (wpart[0] + wpart[1]) + (wpart[2] + wpart[3]);
        atomicAdd(out, s * inv_total);
    }
}

extern "C" void kernel_launch(void* const* d_in, const int* in_sizes, int n_in,
                              void* d_out, int out_size, void* d_ws, size_t ws_size,
                              hipStream_t stream) {
    const float* A = (const float*)d_in[0];
    const float* B = (const float*)d_in[1];
    float* out = (float*)d_out;

    const int total = in_sizes[0];                 // 32*1*512*512
    const int nimg = total / (IMG_H * IMG_W);      // 32

    hipMemsetAsync(d_out, 0, sizeof(float), stream);

    dim3 grid(IMG_H / T, nimg, 1);                 // (128, 32)
    ssim_fused_kernel<<<grid, 256, 0, stream>>>(A, B, out, 1.0f / (float)total);
}